// Round 2
// baseline (571.936 us; speedup 1.0000x reference)
//
#include <hip/hip_runtime.h>
#include <hip/hip_bf16.h>

// Problem constants
#define BB 4
#define SS 4096
#define DM 1024
#define HH 16
#define PP 32
#define RR 8
#define DD 64
#define NTOK (BB*SS)          // 16384 tokens
#define MM NTOK               // GEMM M
#define NN DM                 // GEMM N
#define KK DM                 // GEMM K

typedef __attribute__((ext_vector_type(8))) short short8;
typedef __attribute__((ext_vector_type(4))) float floatx4;

// ---------------------------------------------------------------------------
// Kernel 1: convert W_out (f32 [k][n] row-major) -> bf16, pre-swizzled into
// MFMA B-fragment order (unchanged from R1).
// ---------------------------------------------------------------------------
__global__ __launch_bounds__(256) void convert_w(const float* __restrict__ Wo,
                                                 __hip_bfloat16* __restrict__ wsw) {
    int tid = blockIdx.x * 256 + threadIdx.x;     // 0 .. 131071
    int l = tid & 63;
    int kblk = (tid >> 6) & 31;
    int ntile = tid >> 11;
    int col = ntile * 16 + (l & 15);
    int krow = kblk * 32 + (l >> 4) * 8;
#pragma unroll
    for (int j = 0; j < 8; ++j) {
        wsw[(size_t)tid * 8 + j] = __float2bfloat16(Wo[(size_t)(krow + j) * NN + col]);
    }
}

// ---------------------------------------------------------------------------
// Kernel 2 (v2): router + sparse SSE attention. One wave per (token, head).
// Logits FMA chain kept BITWISE-IDENTICAL to R1 (top-k selection is a
// discontinuity; inputs are fixed, R1's realization verified-passing).
// Changes: b128 LDS x-reads, count-based top-k, batched 4-expert score/head
// phase (lane = e*16 + r*2 + dhalf), v_readlane V-broadcast.
// ---------------------------------------------------------------------------
__global__ __launch_bounds__(256) void attn_kernel(const float* __restrict__ x,
                                                   const float* __restrict__ Kst,
                                                   const float* __restrict__ Vst,
                                                   const float* __restrict__ Wr,
                                                   const int* __restrict__ kp,
                                                   __hip_bfloat16* __restrict__ hb) {
    __shared__ float xs[4][64];
    const int lane = threadIdx.x & 63;
    const int wave = threadIdx.x >> 6;
    const int bid  = blockIdx.x * 4 + wave;       // 0 .. 262143
    const int t = bid & (NTOK - 1);               // token (fast)
    const int h = bid >> 14;                      // head  (slow)

    float xv = x[(size_t)t * DM + h * DD + lane];
    xs[wave][lane] = xv;
    __syncthreads();

    const int kk = kp[0];

    // ---- logits (fp32), identical arithmetic order to R1 ----
    const int p  = lane & 31;
    const int dh = lane >> 5;
    const float* wrow = Wr + (size_t)h * (DD * PP) + dh * 32 * PP + p;

    // preload x slice into registers with wide (broadcast) LDS reads
    float xf[32];
#pragma unroll
    for (int j = 0; j < 8; ++j) {
        float4 tq = *(const float4*)&xs[wave][dh * 32 + 4 * j];
        xf[4 * j + 0] = tq.x; xf[4 * j + 1] = tq.y;
        xf[4 * j + 2] = tq.z; xf[4 * j + 3] = tq.w;
    }

    float lg = 0.f;
#pragma unroll
    for (int dd = 0; dd < 32; ++dd)
        lg += xf[dd] * wrow[dd * PP];
    lg += __shfl_xor(lg, 32);                     // full logit_p in all lanes

    // ---- top-k via count-of-greater (selection identical to R1 butterfly) --
    int cnt = 0;
#pragma unroll
    for (int i = 0; i < 16; ++i) {
        int q = dh * 16 + ((p + i) & 15);         // halves cover disjoint q
        float qv = __shfl(lg, q);
        cnt += (qv > lg || (qv == lg && q < p)) ? 1 : 0;
    }
    cnt += __shfl_xor(cnt, 32);                   // full count (0..31, distinct)

    unsigned long long balt = __ballot(cnt == kk - 1);
    float thresh = __shfl(lg, (int)__ffsll(balt) - 1);   // k-th largest value
    unsigned long long bal0 = __ballot(cnt == 0);
    float m1 = __shfl(lg, (int)__ffsll(bal0) - 1);       // max

    const bool selme = (lg >= thresh);            // ref semantics (>=)
    float ex = selme ? expf(lg - m1) : 0.f;
    float es = ex;
    es += __shfl_xor(es, 1);  es += __shfl_xor(es, 2);  es += __shfl_xor(es, 4);
    es += __shfl_xor(es, 8);  es += __shfl_xor(es, 16);
    const float gate = ex / es;

    unsigned long long bal = __ballot(selme);
    const unsigned sel = (unsigned)(bal & 0xffffffffull);

    // ---- batched expert phase: lane = e*16 + r*2 + dhalf ----
    const int e   = lane >> 4;
    const int rr  = (lane >> 1) & 7;
    const int dhh = lane & 1;

    // x slice for score dots (broadcast reads: 2 distinct addrs per instr)
    float xg[32];
#pragma unroll
    for (int j = 0; j < 8; ++j) {
        float4 tq = *(const float4*)&xs[wave][dhh * 32 + 4 * j];
        xg[4 * j + 0] = tq.x; xg[4 * j + 1] = tq.y;
        xg[4 * j + 2] = tq.z; xg[4 * j + 3] = tq.w;
    }

    float hacc = 0.f;
    unsigned srem = sel;
    while (srem) {                                 // wave-uniform; 1 iter normally
        int p0 = 0, p1 = 0, p2 = 0, p3 = 0, nv = 0;
        if (srem) { p0 = __ffs(srem) - 1; srem &= srem - 1; nv = 1; }
        if (srem) { p1 = __ffs(srem) - 1; srem &= srem - 1; nv = 2; }
        if (srem) { p2 = __ffs(srem) - 1; srem &= srem - 1; nv = 3; }
        if (srem) { p3 = __ffs(srem) - 1; srem &= srem - 1; nv = 4; }

        const int pe = (e == 0) ? p0 : (e == 1) ? p1 : (e == 2) ? p2 : p3;
        float gv = __shfl(gate, pe);
        if (e >= nv) gv = 0.f;

        // score dot: 32 MACs over d = dhh*32 .. +31, K as float4
        const float4* Kp4 = (const float4*)(Kst + (((size_t)h * PP + pe) * RR + rr) * DD + dhh * 32);
        float s = 0.f;
#pragma unroll
        for (int j = 0; j < 8; ++j) {
            float4 kq = Kp4[j];
            s += xg[4 * j + 0] * kq.x; s += xg[4 * j + 1] * kq.y;
            s += xg[4 * j + 2] * kq.z; s += xg[4 * j + 3] * kq.w;
        }
        s += __shfl_xor(s, 1);                     // full dot (both dhh lanes)
        float sc = s * 0.125f;                     // 1/sqrt(D)

        // softmax over r (lanes e*16 + r*2 + dhh, r in xor-bits 1..3)
        float mx = sc;
        mx = fmaxf(mx, __shfl_xor(mx, 2));
        mx = fmaxf(mx, __shfl_xor(mx, 4));
        mx = fmaxf(mx, __shfl_xor(mx, 8));
        float ee = expf(sc - mx);
        float se = ee;
        se += __shfl_xor(se, 2); se += __shfl_xor(se, 4); se += __shfl_xor(se, 8);
        const float w = (ee / se) * gv;            // valid at lanes e*16+r*2(+1)

        // heads accumulation: lane = d; w broadcast via readlane (no DS pipe)
#pragma unroll
        for (int e2 = 0; e2 < 4; ++e2) {
            if (e2 >= nv) break;                   // uniform
            const int pb = (e2 == 0) ? p0 : (e2 == 1) ? p1 : (e2 == 2) ? p2 : p3;
            const float* Vrow = Vst + (((size_t)h * PP + pb) * RR) * DD + lane;
#pragma unroll
            for (int r2 = 0; r2 < 8; ++r2) {
                float wv = __uint_as_float(
                    __builtin_amdgcn_readlane(__float_as_uint(w), e2 * 16 + r2 * 2));
                hacc += wv * Vrow[r2 * DD];
            }
        }
    }

    hb[(size_t)t * DM + h * DD + lane] = __float2bfloat16(hacc);
}

// ---------------------------------------------------------------------------
// Kernel 3: out = heads(bf16) @ W_out(bf16, swizzled) + b_out (unchanged R1).
// ---------------------------------------------------------------------------
__global__ __launch_bounds__(256) void gemm_kernel(const __hip_bfloat16* __restrict__ Abf,
                                                   const __hip_bfloat16* __restrict__ Bsw,
                                                   const float* __restrict__ bias,
                                                   float* __restrict__ C) {
    const int lane = threadIdx.x & 63;
    const int wave = threadIdx.x >> 6;
    const int wm = wave >> 1, wn = wave & 1;
    const int bm0 = blockIdx.y * 128;
    const int bn0 = blockIdx.x * 128;
    const int l15 = lane & 15, l4 = lane >> 4;

    const short* Ap = (const short*)Abf;
    const short* Bp = (const short*)Bsw;

    int aoff[4], boff[4];
#pragma unroll
    for (int mt = 0; mt < 4; ++mt)
        aoff[mt] = (bm0 + wm * 64 + mt * 16 + l15) * KK + l4 * 8;
#pragma unroll
    for (int nt = 0; nt < 4; ++nt)
        boff[nt] = (((bn0 >> 4) + wn * 4 + nt) * 32) * 512 + lane * 8;

    floatx4 acc[4][4] = {};

    for (int kb = 0; kb < 32; ++kb) {
        short8 a[4], b[4];
#pragma unroll
        for (int mt = 0; mt < 4; ++mt)
            a[mt] = *(const short8*)(Ap + aoff[mt] + kb * 32);
#pragma unroll
        for (int nt = 0; nt < 4; ++nt)
            b[nt] = *(const short8*)(Bp + boff[nt] + kb * 512);
#pragma unroll
        for (int mt = 0; mt < 4; ++mt)
#pragma unroll
            for (int nt = 0; nt < 4; ++nt)
                acc[mt][nt] = __builtin_amdgcn_mfma_f32_16x16x32_bf16(a[mt], b[nt], acc[mt][nt], 0, 0, 0);
    }

#pragma unroll
    for (int nt = 0; nt < 4; ++nt) {
        const int col = bn0 + wn * 64 + nt * 16 + l15;
        const float bv = bias[col];
#pragma unroll
        for (int mt = 0; mt < 4; ++mt) {
            const int row0 = bm0 + wm * 64 + mt * 16 + l4 * 4;
#pragma unroll
            for (int i = 0; i < 4; ++i)
                C[(size_t)(row0 + i) * NN + col] = acc[mt][nt][i] + bv;
        }
    }
}

// ---------------------------------------------------------------------------
extern "C" void kernel_launch(void* const* d_in, const int* in_sizes, int n_in,
                              void* d_out, int out_size, void* d_ws, size_t ws_size,
                              hipStream_t stream) {
    const float* x   = (const float*)d_in[0];
    const float* Kst = (const float*)d_in[1];
    const float* Vst = (const float*)d_in[2];
    const float* Wr  = (const float*)d_in[3];
    const float* Wo  = (const float*)d_in[4];
    const float* bo  = (const float*)d_in[5];
    const int*   kp  = (const int*)d_in[6];
    float* out = (float*)d_out;

    __hip_bfloat16* hb  = (__hip_bfloat16*)d_ws;                 // 16384x1024 bf16 = 32 MiB
    __hip_bfloat16* wsw = hb + (size_t)MM * KK;                  // 1024x1024 bf16 = 2 MiB

    convert_w<<<dim3(512), 256, 0, stream>>>(Wo, wsw);
    attn_kernel<<<dim3(NTOK * HH / 4), 256, 0, stream>>>(x, Kst, Vst, Wr, kp, hb);
    gemm_kernel<<<dim3(NN / 128, MM / 128), 256, 0, stream>>>(hb, wsw, bo, out);
}

// Round 3
// 291.300 us; speedup vs baseline: 1.9634x; 1.9634x over previous
//
#include <hip/hip_runtime.h>
#include <hip/hip_bf16.h>

// Problem constants
#define BB 4
#define SS 4096
#define DM 1024
#define HH 16
#define PP 32
#define RR 8
#define DD 64
#define NTOK (BB*SS)          // 16384 tokens
#define MM NTOK               // GEMM M
#define NN DM                 // GEMM N
#define KK DM                 // GEMM K

typedef __attribute__((ext_vector_type(8))) short short8;
typedef __attribute__((ext_vector_type(4))) float floatx4;

static __device__ inline short f2bf(float f) {
    union { __hip_bfloat16 b; short s; } u; u.b = __float2bfloat16(f); return u.s;
}
static __device__ inline short8 pack8(float4 lo, float4 hi) {
    short8 r;
    r[0] = f2bf(lo.x); r[1] = f2bf(lo.y); r[2] = f2bf(lo.z); r[3] = f2bf(lo.w);
    r[4] = f2bf(hi.x); r[5] = f2bf(hi.y); r[6] = f2bf(hi.z); r[7] = f2bf(hi.w);
    return r;
}

// ---------------------------------------------------------------------------
// Kernel 1: W_out (f32 [k][n]) -> bf16 MFMA B-fragment order (unchanged R1).
// ---------------------------------------------------------------------------
__global__ __launch_bounds__(256) void convert_w(const float* __restrict__ Wo,
                                                 __hip_bfloat16* __restrict__ wsw) {
    int tid = blockIdx.x * 256 + threadIdx.x;     // 0 .. 131071
    int l = tid & 63;
    int kblk = (tid >> 6) & 31;
    int ntile = tid >> 11;
    int col = ntile * 16 + (l & 15);
    int krow = kblk * 32 + (l >> 4) * 8;
#pragma unroll
    for (int j = 0; j < 8; ++j) {
        wsw[(size_t)tid * 8 + j] = __float2bfloat16(Wo[(size_t)(krow + j) * NN + col]);
    }
}

// ---------------------------------------------------------------------------
// Kernel 1b: K_state -> A-frag layout for scores GEMM (m=pr, k=d);
//            V_state -> A-frag layout for heads GEMM (m=d, k=pr, i.e. V^T).
// kfrag[h]: blocks (mt 0..15 over pr, kb 0..1 over d), 512 bf16/block,
//   element flane*8+j = K[h][pr=mt*16+(flane&15)][d=kb*32+(flane>>4)*8+j]
// vfrag[h]: blocks (mt 0..3 over d, kb 0..7 over pr),
//   element flane*8+j = V[h][pr=kb*32+(flane>>4)*8+j][d=mt*16+(flane&15)]
// ---------------------------------------------------------------------------
__global__ __launch_bounds__(256) void convert_kv(const float* __restrict__ Kst,
                                                  const float* __restrict__ Vst,
                                                  __hip_bfloat16* __restrict__ kfrag,
                                                  __hip_bfloat16* __restrict__ vfrag) {
    int tid = blockIdx.x * 256 + threadIdx.x;     // 0..65535
    int arr = tid >> 15;
    int idx = tid & 32767;
    int h = idx >> 11, blk = (idx >> 6) & 31, fl = idx & 63;
    int fm = fl & 15, fk = fl >> 4;
    short8 val;
    short* dst;
    if (arr == 0) {
        int mt = blk >> 1, kb = blk & 1;
        int pr = mt * 16 + fm, d0 = kb * 32 + fk * 8;
        const float* src = Kst + ((size_t)h * 256 + pr) * 64 + d0;
        float4 lo = *(const float4*)src, hi = *(const float4*)(src + 4);
        val = pack8(lo, hi);
        dst = (short*)kfrag + (size_t)idx * 8;
    } else {
        int mt = blk >> 3, kb = blk & 7;
        int d = mt * 16 + fm, pr0 = kb * 32 + fk * 8;
        const float* src = Vst + ((size_t)h * 256 + pr0) * 64 + d;
#pragma unroll
        for (int j = 0; j < 8; ++j) val[j] = f2bf(src[j * 64]);
        dst = (short*)vfrag + (size_t)idx * 8;
    }
    *(short8*)dst = val;
}

// ---------------------------------------------------------------------------
// Kernel 2 (v3): fused router + dense-MFMA SSE attention.
// Block = 64 tokens x 1 head, 256 threads (4 waves).
// Phases: stage x -> scores MFMA (S^T[pr][t]) -> exact fp32 logits ->
//         in-register top-k/gates -> r-softmax+gate -> w B-frags (LDS) ->
//         heads MFMA (H^T = V^T @ w) -> bf16 store to hb.
// ---------------------------------------------------------------------------
__global__ __launch_bounds__(256, 2) void attn_v3(const float* __restrict__ x,
                                                  const float* __restrict__ Wr,
                                                  const __hip_bfloat16* __restrict__ kfrag,
                                                  const __hip_bfloat16* __restrict__ vfrag,
                                                  const int* __restrict__ kp,
                                                  __hip_bfloat16* __restrict__ hb) {
    __shared__ __align__(16) float xs[64][68];    // stride 68: 16B-aligned rows
    __shared__ __align__(16) float Lg[64][36];
    __shared__ __align__(16) float gates[64][36];
    __shared__ __align__(16) short wf[16384];     // 32 KB w B-frags

    const int lane = threadIdx.x & 63;
    const int w = threadIdx.x >> 6;
    const int l15 = lane & 15, l4 = lane >> 4;
    const int t0 = blockIdx.x * 64;
    const int h = blockIdx.y;

    // ---- stage x tile [64 t x 64 d] into LDS ----
    {
        int row = threadIdx.x >> 2, q = threadIdx.x & 3;
        const float4* src = (const float4*)(x + (size_t)(t0 + row) * DM + h * 64 + q * 16);
        float4 v0 = src[0], v1 = src[1], v2 = src[2], v3 = src[3];
        float4* dst = (float4*)&xs[row][q * 16];
        dst[0] = v0; dst[1] = v1; dst[2] = v2; dst[3] = v3;
    }

    // ---- preload router weights (exact R1 pattern) ----
    const int p = lane & 31, dh = lane >> 5;
    float wreg[32];
    {
        const float* wrp = Wr + (size_t)h * (DD * PP) + dh * 32 * PP + p;
#pragma unroll
        for (int dd = 0; dd < 32; ++dd) wreg[dd] = wrp[dd * PP];
    }
    const int kkv = kp[0];

    __syncthreads();

    // ---- scores GEMM: S^T[pr][t]; A = kfrag (global), B = x (global) ----
    short8 xb[4][2];
#pragma unroll
    for (int nt = 0; nt < 4; ++nt)
#pragma unroll
        for (int kb = 0; kb < 2; ++kb) {
            const float* bp = x + (size_t)(t0 + nt * 16 + l15) * DM + h * 64 + kb * 32 + l4 * 8;
            float4 lo = *(const float4*)bp;
            float4 hi = *(const float4*)(bp + 4);
            xb[nt][kb] = pack8(lo, hi);
        }
    short8 ka[4][2];
#pragma unroll
    for (int mi = 0; mi < 4; ++mi)
#pragma unroll
        for (int kb = 0; kb < 2; ++kb)
            ka[mi][kb] = *(const short8*)((const short*)kfrag +
                          ((size_t)(h * 32 + (w * 4 + mi) * 2 + kb) * 512 + lane * 8));

    floatx4 acc[4][4] = {};
#pragma unroll
    for (int kb = 0; kb < 2; ++kb)
#pragma unroll
        for (int mi = 0; mi < 4; ++mi)
#pragma unroll
            for (int nt = 0; nt < 4; ++nt)
                acc[mi][nt] = __builtin_amdgcn_mfma_f32_16x16x32_bf16(ka[mi][kb], xb[nt][kb], acc[mi][nt], 0, 0, 0);

    // ---- logits: arithmetic chain bitwise-identical to R1/R2 ----
    for (int it = 0; it < 16; ++it) {
        int t = w * 16 + it;
        float xf[32];
#pragma unroll
        for (int j = 0; j < 8; ++j) {
            float4 tq = *(const float4*)&xs[t][dh * 32 + 4 * j];
            xf[4 * j] = tq.x; xf[4 * j + 1] = tq.y; xf[4 * j + 2] = tq.z; xf[4 * j + 3] = tq.w;
        }
        float lg = 0.f;
#pragma unroll
        for (int dd = 0; dd < 32; ++dd) lg += xf[dd] * wreg[dd];
        lg += __shfl_xor(lg, 32);
        if (lane < 32) Lg[t][lane] = lg;
    }
    __syncthreads();

    // ---- top-k + gates, in-register per token (lanes 0..15) ----
    if (lane < 16) {
        int t = w * 16 + lane;
        float lgr[32];
        const float4* lrow = (const float4*)&Lg[t][0];
#pragma unroll
        for (int c = 0; c < 8; ++c) {
            float4 q4 = lrow[c];
            lgr[4 * c] = q4.x; lgr[4 * c + 1] = q4.y; lgr[4 * c + 2] = q4.z; lgr[4 * c + 3] = q4.w;
        }
        // branchless top-4 values (thresh = 4th largest VALUE = ref topv[...,-1])
        float a1 = -INFINITY, b2 = -INFINITY, c3 = -INFINITY, d4 = -INFINITY;
#pragma unroll
        for (int pp = 0; pp < 32; ++pp) {
            float v = lgr[pp];
            float na = fmaxf(a1, v); v = fminf(a1, v); a1 = na;
            float nb = fmaxf(b2, v); v = fminf(b2, v); b2 = nb;
            float nc = fmaxf(c3, v); v = fminf(c3, v); c3 = nc;
            d4 = fmaxf(d4, v);
        }
        float thresh = (kkv >= 4) ? d4 : (kkv == 3 ? c3 : (kkv == 2 ? b2 : a1));
        float den = 0.f;
        float garr[32];
#pragma unroll
        for (int pp = 0; pp < 32; ++pp) {
            float e = __expf(lgr[pp] - a1);
            float ge = (lgr[pp] >= thresh) ? e : 0.f;   // ref semantics: >=
            garr[pp] = ge; den += ge;
        }
        float inv = 1.f / den;
        float4* grow = (float4*)&gates[t][0];
#pragma unroll
        for (int c = 0; c < 8; ++c)
            grow[c] = make_float4(garr[4 * c] * inv, garr[4 * c + 1] * inv,
                                  garr[4 * c + 2] * inv, garr[4 * c + 3] * inv);
    }
    __syncthreads();

    // ---- r-softmax + gate -> w B-frags in LDS ----
    // C layout: row(pr within tile) = l4*4+i, col(t) = l15.
    // p = mt*2 + (l4>>1); r = (l4&1)*4 + i; partner over r-halves = xor(16).
#pragma unroll
    for (int mi = 0; mi < 4; ++mi) {
        const int mt = w * 4 + mi;
        const int pidx = mt * 2 + (l4 >> 1);
#pragma unroll
        for (int nt = 0; nt < 4; ++nt) {
            float g = gates[nt * 16 + l15][pidx];
            float s0 = acc[mi][nt][0] * 0.125f;
            float s1 = acc[mi][nt][1] * 0.125f;
            float s2 = acc[mi][nt][2] * 0.125f;
            float s3 = acc[mi][nt][3] * 0.125f;
            float mx = fmaxf(fmaxf(s0, s1), fmaxf(s2, s3));
            mx = fmaxf(mx, __shfl_xor(mx, 16));
            float e0 = __expf(s0 - mx), e1 = __expf(s1 - mx);
            float e2 = __expf(s2 - mx), e3 = __expf(s3 - mx);
            float loc = (e0 + e1) + (e2 + e3);
            float se = loc + __shfl_xor(loc, 16);
            float ws = g / se;
            short q0 = f2bf(e0 * ws), q1 = f2bf(e1 * ws);
            short q2 = f2bf(e2 * ws), q3 = f2bf(e3 * ws);
            int2 pk;
            pk.x = ((int)q0 & 0xffff) | ((int)q1 << 16);
            pk.y = ((int)q2 & 0xffff) | ((int)q3 << 16);
            int off = (((mt & 1) * 2 + (l4 >> 1)) * 16 + l15) * 8 + (l4 & 1) * 4;
            *(int2*)&wf[(nt * 8 + (mt >> 1)) * 512 + off] = pk;
        }
    }
    __syncthreads();

    // ---- heads GEMM: H^T[d][t] = Vfrag(A) @ wf(B) ----
    floatx4 h4[4] = {};
#pragma unroll
    for (int kb = 0; kb < 8; ++kb) {
        short8 va = *(const short8*)((const short*)vfrag +
                      ((size_t)(h * 32 + w * 8 + kb) * 512 + lane * 8));
#pragma unroll
        for (int nt = 0; nt < 4; ++nt) {
            short8 wb = *(const short8*)&wf[(nt * 8 + kb) * 512 + lane * 8];
            h4[nt] = __builtin_amdgcn_mfma_f32_16x16x32_bf16(va, wb, h4[nt], 0, 0, 0);
        }
    }
    // store: H^T[d = w*16 + l4*4 + i][t = t0 + nt*16 + l15] -> hb[t][h*64 + d]
#pragma unroll
    for (int nt = 0; nt < 4; ++nt) {
        int t = t0 + nt * 16 + l15;
        short q0 = f2bf(h4[nt][0]), q1 = f2bf(h4[nt][1]);
        short q2 = f2bf(h4[nt][2]), q3 = f2bf(h4[nt][3]);
        int2 pk;
        pk.x = ((int)q0 & 0xffff) | ((int)q1 << 16);
        pk.y = ((int)q2 & 0xffff) | ((int)q3 << 16);
        *(int2*)((short*)hb + (size_t)t * DM + h * 64 + w * 16 + l4 * 4) = pk;
    }
}

// ---------------------------------------------------------------------------
// Kernel 3: out = heads(bf16) @ W_out(bf16, swizzled) + b_out (unchanged R1).
// ---------------------------------------------------------------------------
__global__ __launch_bounds__(256) void gemm_kernel(const __hip_bfloat16* __restrict__ Abf,
                                                   const __hip_bfloat16* __restrict__ Bsw,
                                                   const float* __restrict__ bias,
                                                   float* __restrict__ C) {
    const int lane = threadIdx.x & 63;
    const int wave = threadIdx.x >> 6;
    const int wm = wave >> 1, wn = wave & 1;
    const int bm0 = blockIdx.y * 128;
    const int bn0 = blockIdx.x * 128;
    const int l15 = lane & 15, l4 = lane >> 4;

    const short* Ap = (const short*)Abf;
    const short* Bp = (const short*)Bsw;

    int aoff[4], boff[4];
#pragma unroll
    for (int mt = 0; mt < 4; ++mt)
        aoff[mt] = (bm0 + wm * 64 + mt * 16 + l15) * KK + l4 * 8;
#pragma unroll
    for (int nt = 0; nt < 4; ++nt)
        boff[nt] = (((bn0 >> 4) + wn * 4 + nt) * 32) * 512 + lane * 8;

    floatx4 acc[4][4] = {};

    for (int kb = 0; kb < 32; ++kb) {
        short8 a[4], b[4];
#pragma unroll
        for (int mt = 0; mt < 4; ++mt)
            a[mt] = *(const short8*)(Ap + aoff[mt] + kb * 32);
#pragma unroll
        for (int nt = 0; nt < 4; ++nt)
            b[nt] = *(const short8*)(Bp + boff[nt] + kb * 512);
#pragma unroll
        for (int mt = 0; mt < 4; ++mt)
#pragma unroll
            for (int nt = 0; nt < 4; ++nt)
                acc[mt][nt] = __builtin_amdgcn_mfma_f32_16x16x32_bf16(a[mt], b[nt], acc[mt][nt], 0, 0, 0);
    }

#pragma unroll
    for (int nt = 0; nt < 4; ++nt) {
        const int col = bn0 + wn * 64 + nt * 16 + l15;
        const float bv = bias[col];
#pragma unroll
        for (int mt = 0; mt < 4; ++mt) {
            const int row0 = bm0 + wm * 64 + mt * 16 + l4 * 4;
#pragma unroll
            for (int i = 0; i < 4; ++i)
                C[(size_t)(row0 + i) * NN + col] = acc[mt][nt][i] + bv;
        }
    }
}

// ---------------------------------------------------------------------------
extern "C" void kernel_launch(void* const* d_in, const int* in_sizes, int n_in,
                              void* d_out, int out_size, void* d_ws, size_t ws_size,
                              hipStream_t stream) {
    const float* x   = (const float*)d_in[0];
    const float* Kst = (const float*)d_in[1];
    const float* Vst = (const float*)d_in[2];
    const float* Wr  = (const float*)d_in[3];
    const float* Wo  = (const float*)d_in[4];
    const float* bo  = (const float*)d_in[5];
    const int*   kp  = (const int*)d_in[6];
    float* out = (float*)d_out;

    __hip_bfloat16* hb    = (__hip_bfloat16*)d_ws;             // 16M bf16 = 32 MiB
    __hip_bfloat16* wsw   = hb + (size_t)MM * KK;              // 1M bf16  = 2 MiB
    __hip_bfloat16* kfrag = wsw + (size_t)KK * NN;             // 256K bf16
    __hip_bfloat16* vfrag = kfrag + 16 * 32 * 512;             // 256K bf16

    convert_w<<<dim3(512), 256, 0, stream>>>(Wo, wsw);
    convert_kv<<<dim3(256), 256, 0, stream>>>(Kst, Vst, kfrag, vfrag);
    attn_v3<<<dim3(NTOK / 64, HH), 256, 0, stream>>>(x, Wr, kfrag, vfrag, kp, hb);
    gemm_kernel<<<dim3(NN / 128, MM / 128), 256, 0, stream>>>(hb, wsw, bo, out);
}

// Round 4
// 264.052 us; speedup vs baseline: 2.1660x; 1.1032x over previous
//
#include <hip/hip_runtime.h>
#include <hip/hip_bf16.h>

// Problem constants
#define BB 4
#define SS 4096
#define DM 1024
#define HH 16
#define PP 32
#define RR 8
#define DD 64
#define NTOK (BB*SS)          // 16384 tokens
#define MM NTOK               // GEMM M
#define NN DM                 // GEMM N
#define KK DM                 // GEMM K

typedef __attribute__((ext_vector_type(8))) short short8;
typedef __attribute__((ext_vector_type(4))) float floatx4;

static __device__ inline short f2bf(float f) {
    union { __hip_bfloat16 b; short s; } u; u.b = __float2bfloat16(f); return u.s;
}
static __device__ inline short8 pack8(float4 lo, float4 hi) {
    short8 r;
    r[0] = f2bf(lo.x); r[1] = f2bf(lo.y); r[2] = f2bf(lo.z); r[3] = f2bf(lo.w);
    r[4] = f2bf(hi.x); r[5] = f2bf(hi.y); r[6] = f2bf(hi.z); r[7] = f2bf(hi.w);
    return r;
}

// Fast RNE bf16 pack: identical bits to __float2bfloat16 for finite inputs.
static __device__ inline unsigned bfr(float f) {
    unsigned u = __float_as_uint(f);
    return u + 0x7fffu + ((u >> 16) & 1u);
}
static __device__ inline int pk2(float a, float b) {  // low16=bf(a), high16=bf(b)
    return __builtin_amdgcn_perm(bfr(b), bfr(a), 0x07060302);
}
static __device__ inline short8 pk8(float4 lo, float4 hi) {
    union { short8 s; int i[4]; } r;
    r.i[0] = pk2(lo.x, lo.y); r.i[1] = pk2(lo.z, lo.w);
    r.i[2] = pk2(hi.x, hi.y); r.i[3] = pk2(hi.z, hi.w);
    return r.s;
}

// ---------------------------------------------------------------------------
// Kernel 1: W_out (f32 [k][n]) -> bf16 MFMA B-fragment order (unchanged).
// ---------------------------------------------------------------------------
__global__ __launch_bounds__(256) void convert_w(const float* __restrict__ Wo,
                                                 __hip_bfloat16* __restrict__ wsw) {
    int tid = blockIdx.x * 256 + threadIdx.x;     // 0 .. 131071
    int l = tid & 63;
    int kblk = (tid >> 6) & 31;
    int ntile = tid >> 11;
    int col = ntile * 16 + (l & 15);
    int krow = kblk * 32 + (l >> 4) * 8;
#pragma unroll
    for (int j = 0; j < 8; ++j) {
        wsw[(size_t)tid * 8 + j] = __float2bfloat16(Wo[(size_t)(krow + j) * NN + col]);
    }
}

// ---------------------------------------------------------------------------
// Kernel 1b: K_state / V_state -> MFMA A-frag layouts (unchanged from R3).
// ---------------------------------------------------------------------------
__global__ __launch_bounds__(256) void convert_kv(const float* __restrict__ Kst,
                                                  const float* __restrict__ Vst,
                                                  __hip_bfloat16* __restrict__ kfrag,
                                                  __hip_bfloat16* __restrict__ vfrag) {
    int tid = blockIdx.x * 256 + threadIdx.x;     // 0..65535
    int arr = tid >> 15;
    int idx = tid & 32767;
    int h = idx >> 11, blk = (idx >> 6) & 31, fl = idx & 63;
    int fm = fl & 15, fk = fl >> 4;
    short8 val;
    short* dst;
    if (arr == 0) {
        int mt = blk >> 1, kb = blk & 1;
        int pr = mt * 16 + fm, d0 = kb * 32 + fk * 8;
        const float* src = Kst + ((size_t)h * 256 + pr) * 64 + d0;
        float4 lo = *(const float4*)src, hi = *(const float4*)(src + 4);
        val = pack8(lo, hi);
        dst = (short*)kfrag + (size_t)idx * 8;
    } else {
        int mt = blk >> 3, kb = blk & 7;
        int d = mt * 16 + fm, pr0 = kb * 32 + fk * 8;
        const float* src = Vst + ((size_t)h * 256 + pr0) * 64 + d;
#pragma unroll
        for (int j = 0; j < 8; ++j) val[j] = f2bf(src[j * 64]);
        dst = (short*)vfrag + (size_t)idx * 8;
    }
    *(short8*)dst = val;
}

// ---------------------------------------------------------------------------
// Kernel 2 (v4): fused router + dense-MFMA SSE attention.
// Changes vs v3: LDS aliasing (xs,Lg dead before wf is written -> union;
// 68.6 KB -> 41 KB -> 3 blocks/CU) and fast RNE bf16 packing (pk2/pk8,
// bit-identical). Numerics identical to the verified R3 kernel.
// ---------------------------------------------------------------------------
__global__ __launch_bounds__(256, 3) void attn_v4(const float* __restrict__ x,
                                                  const float* __restrict__ Wr,
                                                  const __hip_bfloat16* __restrict__ kfrag,
                                                  const __hip_bfloat16* __restrict__ vfrag,
                                                  const int* __restrict__ kp,
                                                  __hip_bfloat16* __restrict__ hb) {
    // Aliased LDS region (41984 B total):
    //   [0,32768):  wf (heads-phase B-frags)  -- written after top-k sync
    //   [0,17408):  xs[64][68]                -- dead after logits phase
    //   [17408,26624): Lg[64][36]             -- dead after top-k phase
    //   [32768,41984): gates[64][36]          -- live during wf phase (disjoint)
    __shared__ __align__(16) char smem[41984];
    float (*xs)[68]    = (float (*)[68])smem;
    float (*Lg)[36]    = (float (*)[36])(smem + 17408);
    short* wf          = (short*)smem;
    float (*gates)[36] = (float (*)[36])(smem + 32768);

    const int lane = threadIdx.x & 63;
    const int w = threadIdx.x >> 6;
    const int l15 = lane & 15, l4 = lane >> 4;
    const int t0 = blockIdx.x * 64;
    const int h = blockIdx.y;

    // ---- stage x tile [64 t x 64 d] into LDS ----
    {
        int row = threadIdx.x >> 2, q = threadIdx.x & 3;
        const float4* src = (const float4*)(x + (size_t)(t0 + row) * DM + h * 64 + q * 16);
        float4 v0 = src[0], v1 = src[1], v2 = src[2], v3 = src[3];
        float4* dst = (float4*)&xs[row][q * 16];
        dst[0] = v0; dst[1] = v1; dst[2] = v2; dst[3] = v3;
    }

    // ---- preload router weights (exact R1 pattern) ----
    const int p = lane & 31, dh = lane >> 5;
    float wreg[32];
    {
        const float* wrp = Wr + (size_t)h * (DD * PP) + dh * 32 * PP + p;
#pragma unroll
        for (int dd = 0; dd < 32; ++dd) wreg[dd] = wrp[dd * PP];
    }
    const int kkv = kp[0];

    __syncthreads();

    // ---- scores GEMM: S^T[pr][t]; A = kfrag (global), B = x (global) ----
    short8 xb[4][2];
#pragma unroll
    for (int nt = 0; nt < 4; ++nt)
#pragma unroll
        for (int kb = 0; kb < 2; ++kb) {
            const float* bp = x + (size_t)(t0 + nt * 16 + l15) * DM + h * 64 + kb * 32 + l4 * 8;
            float4 lo = *(const float4*)bp;
            float4 hi = *(const float4*)(bp + 4);
            xb[nt][kb] = pk8(lo, hi);
        }
    short8 ka[4][2];
#pragma unroll
    for (int mi = 0; mi < 4; ++mi)
#pragma unroll
        for (int kb = 0; kb < 2; ++kb)
            ka[mi][kb] = *(const short8*)((const short*)kfrag +
                          ((size_t)(h * 32 + (w * 4 + mi) * 2 + kb) * 512 + lane * 8));

    floatx4 acc[4][4] = {};
#pragma unroll
    for (int kb = 0; kb < 2; ++kb)
#pragma unroll
        for (int mi = 0; mi < 4; ++mi)
#pragma unroll
            for (int nt = 0; nt < 4; ++nt)
                acc[mi][nt] = __builtin_amdgcn_mfma_f32_16x16x32_bf16(ka[mi][kb], xb[nt][kb], acc[mi][nt], 0, 0, 0);

    // ---- logits: arithmetic chain bitwise-identical to R1/R2/R3 ----
    for (int it = 0; it < 16; ++it) {
        int t = w * 16 + it;
        float xf[32];
#pragma unroll
        for (int j = 0; j < 8; ++j) {
            float4 tq = *(const float4*)&xs[t][dh * 32 + 4 * j];
            xf[4 * j] = tq.x; xf[4 * j + 1] = tq.y; xf[4 * j + 2] = tq.z; xf[4 * j + 3] = tq.w;
        }
        float lg = 0.f;
#pragma unroll
        for (int dd = 0; dd < 32; ++dd) lg += xf[dd] * wreg[dd];
        lg += __shfl_xor(lg, 32);
        if (lane < 32) Lg[t][lane] = lg;
    }
    __syncthreads();

    // ---- top-k + gates, in-register per token (lanes 0..15) ----
    if (lane < 16) {
        int t = w * 16 + lane;
        float lgr[32];
        const float4* lrow = (const float4*)&Lg[t][0];
#pragma unroll
        for (int c = 0; c < 8; ++c) {
            float4 q4 = lrow[c];
            lgr[4 * c] = q4.x; lgr[4 * c + 1] = q4.y; lgr[4 * c + 2] = q4.z; lgr[4 * c + 3] = q4.w;
        }
        float a1 = -INFINITY, b2 = -INFINITY, c3 = -INFINITY, d4 = -INFINITY;
#pragma unroll
        for (int pp = 0; pp < 32; ++pp) {
            float v = lgr[pp];
            float na = fmaxf(a1, v); v = fminf(a1, v); a1 = na;
            float nb = fmaxf(b2, v); v = fminf(b2, v); b2 = nb;
            float nc = fmaxf(c3, v); v = fminf(c3, v); c3 = nc;
            d4 = fmaxf(d4, v);
        }
        float thresh = (kkv >= 4) ? d4 : (kkv == 3 ? c3 : (kkv == 2 ? b2 : a1));
        float den = 0.f;
        float garr[32];
#pragma unroll
        for (int pp = 0; pp < 32; ++pp) {
            float e = __expf(lgr[pp] - a1);
            float ge = (lgr[pp] >= thresh) ? e : 0.f;   // ref semantics: >=
            garr[pp] = ge; den += ge;
        }
        float inv = 1.f / den;
        float4* grow = (float4*)&gates[t][0];
#pragma unroll
        for (int c = 0; c < 8; ++c)
            grow[c] = make_float4(garr[4 * c] * inv, garr[4 * c + 1] * inv,
                                  garr[4 * c + 2] * inv, garr[4 * c + 3] * inv);
    }
    __syncthreads();

    // ---- r-softmax + gate -> w B-frags in LDS (overwrites dead xs/Lg) ----
#pragma unroll
    for (int mi = 0; mi < 4; ++mi) {
        const int mt = w * 4 + mi;
        const int pidx = mt * 2 + (l4 >> 1);
#pragma unroll
        for (int nt = 0; nt < 4; ++nt) {
            float g = gates[nt * 16 + l15][pidx];
            float s0 = acc[mi][nt][0] * 0.125f;
            float s1 = acc[mi][nt][1] * 0.125f;
            float s2 = acc[mi][nt][2] * 0.125f;
            float s3 = acc[mi][nt][3] * 0.125f;
            float mx = fmaxf(fmaxf(s0, s1), fmaxf(s2, s3));
            mx = fmaxf(mx, __shfl_xor(mx, 16));
            float e0 = __expf(s0 - mx), e1 = __expf(s1 - mx);
            float e2 = __expf(s2 - mx), e3 = __expf(s3 - mx);
            float loc = (e0 + e1) + (e2 + e3);
            float se = loc + __shfl_xor(loc, 16);
            float ws = g / se;
            int2 pk;
            pk.x = pk2(e0 * ws, e1 * ws);
            pk.y = pk2(e2 * ws, e3 * ws);
            int off = (((mt & 1) * 2 + (l4 >> 1)) * 16 + l15) * 8 + (l4 & 1) * 4;
            *(int2*)&wf[(nt * 8 + (mt >> 1)) * 512 + off] = pk;
        }
    }
    __syncthreads();

    // ---- heads GEMM: H^T[d][t] = Vfrag(A) @ wf(B) ----
    floatx4 h4[4] = {};
#pragma unroll
    for (int kb = 0; kb < 8; ++kb) {
        short8 va = *(const short8*)((const short*)vfrag +
                      ((size_t)(h * 32 + w * 8 + kb) * 512 + lane * 8));
#pragma unroll
        for (int nt = 0; nt < 4; ++nt) {
            short8 wb = *(const short8*)&wf[(nt * 8 + kb) * 512 + lane * 8];
            h4[nt] = __builtin_amdgcn_mfma_f32_16x16x32_bf16(va, wb, h4[nt], 0, 0, 0);
        }
    }
#pragma unroll
    for (int nt = 0; nt < 4; ++nt) {
        int t = t0 + nt * 16 + l15;
        int2 pk;
        pk.x = pk2(h4[nt][0], h4[nt][1]);
        pk.y = pk2(h4[nt][2], h4[nt][3]);
        *(int2*)((short*)hb + (size_t)t * DM + h * 64 + w * 16 + l4 * 4) = pk;
    }
}

// ---------------------------------------------------------------------------
// Kernel 3 (v2): m97-style GEMM. A (hb) staged via global_load_lds width=16,
// B pre-swizzled read direct (perfectly coalesced), 16 MFMA/wave/K-step.
// MFMA sequence identical to v1 -> bit-identical output.
// ---------------------------------------------------------------------------
__global__ __launch_bounds__(256) void gemm_v2(const __hip_bfloat16* __restrict__ Abf,
                                               const __hip_bfloat16* __restrict__ Bsw,
                                               const float* __restrict__ bias,
                                               float* __restrict__ C) {
    __shared__ __align__(16) short As[4096];      // 128 rows x 32 k = 8 KB
    const int lane = threadIdx.x & 63;
    const int wave = threadIdx.x >> 6;
    const int wm = wave >> 1, wn = wave & 1;
    const int bm0 = blockIdx.y * 128;
    const int bn0 = blockIdx.x * 128;
    const int l15 = lane & 15, l4 = lane >> 4;

    const short* Ap = (const short*)Abf;
    const short* Bp = (const short*)Bsw;

    // staging: chunk c (0..511): row=c>>2 of A-tile, koff=(c&3)*8.
    // wave-instr j in {0,1}: c = (wave*2+j)*64 + lane; LDS linear at c*16B.
    const int c0 = (wave * 2 + 0) * 64 + lane;
    const int c1 = (wave * 2 + 1) * 64 + lane;
    const short* g0 = Ap + (size_t)(bm0 + (c0 >> 2)) * KK + (c0 & 3) * 8;
    const short* g1 = Ap + (size_t)(bm0 + (c1 >> 2)) * KK + (c1 & 3) * 8;
    short* l0 = &As[(wave * 2 + 0) * 512];
    short* l1 = &As[(wave * 2 + 1) * 512];

    int boff[4];
#pragma unroll
    for (int nt = 0; nt < 4; ++nt)
        boff[nt] = (((bn0 >> 4) + wn * 4 + nt) * 32) * 512 + lane * 8;

    int aoff[4];
#pragma unroll
    for (int mt = 0; mt < 4; ++mt)
        aoff[mt] = ((wm * 64 + mt * 16 + l15) * 4 + l4) * 8;

    floatx4 acc[4][4] = {};

    for (int kb = 0; kb < 32; ++kb) {
        __syncthreads();                          // prev frag reads complete
        short8 b[4];
#pragma unroll
        for (int nt = 0; nt < 4; ++nt)
            b[nt] = *(const short8*)(Bp + boff[nt] + kb * 512);
        __builtin_amdgcn_global_load_lds(
            (const __attribute__((address_space(1))) unsigned int*)(g0 + kb * 32),
            (__attribute__((address_space(3))) unsigned int*)l0, 16, 0, 0);
        __builtin_amdgcn_global_load_lds(
            (const __attribute__((address_space(1))) unsigned int*)(g1 + kb * 32),
            (__attribute__((address_space(3))) unsigned int*)l1, 16, 0, 0);
        __syncthreads();                          // staged (vmcnt drained)
        short8 a[4];
#pragma unroll
        for (int mt = 0; mt < 4; ++mt)
            a[mt] = *(const short8*)&As[aoff[mt]];
#pragma unroll
        for (int mt = 0; mt < 4; ++mt)
#pragma unroll
            for (int nt = 0; nt < 4; ++nt)
                acc[mt][nt] = __builtin_amdgcn_mfma_f32_16x16x32_bf16(a[mt], b[nt], acc[mt][nt], 0, 0, 0);
    }

#pragma unroll
    for (int nt = 0; nt < 4; ++nt) {
        const int col = bn0 + wn * 64 + nt * 16 + l15;
        const float bv = bias[col];
#pragma unroll
        for (int mt = 0; mt < 4; ++mt) {
            const int row0 = bm0 + wm * 64 + mt * 16 + l4 * 4;
#pragma unroll
            for (int i = 0; i < 4; ++i)
                C[(size_t)(row0 + i) * NN + col] = acc[mt][nt][i] + bv;
        }
    }
}

// ---------------------------------------------------------------------------
extern "C" void kernel_launch(void* const* d_in, const int* in_sizes, int n_in,
                              void* d_out, int out_size, void* d_ws, size_t ws_size,
                              hipStream_t stream) {
    const float* x   = (const float*)d_in[0];
    const float* Kst = (const float*)d_in[1];
    const float* Vst = (const float*)d_in[2];
    const float* Wr  = (const float*)d_in[3];
    const float* Wo  = (const float*)d_in[4];
    const float* bo  = (const float*)d_in[5];
    const int*   kp  = (const int*)d_in[6];
    float* out = (float*)d_out;

    __hip_bfloat16* hb    = (__hip_bfloat16*)d_ws;             // 16M bf16 = 32 MiB
    __hip_bfloat16* wsw   = hb + (size_t)MM * KK;              // 1M bf16  = 2 MiB
    __hip_bfloat16* kfrag = wsw + (size_t)KK * NN;             // 256K bf16
    __hip_bfloat16* vfrag = kfrag + 16 * 32 * 512;             // 256K bf16

    convert_w<<<dim3(512), 256, 0, stream>>>(Wo, wsw);
    convert_kv<<<dim3(256), 256, 0, stream>>>(Kst, Vst, kfrag, vfrag);
    attn_v4<<<dim3(NTOK / 64, HH), 256, 0, stream>>>(x, Wr, kfrag, vfrag, kp, hb);
    gemm_v2<<<dim3(NN / 128, MM / 128), 256, 0, stream>>>(hb, wsw, bo, out);
}